// Round 1
// baseline (491.065 us; speedup 1.0000x reference)
//
#include <hip/hip_runtime.h>
#include <math.h>

#define BATCH 4096
#define NC    8192
#define DIM   512
#define KEXP  5

// ---------------------------------------------------------------------------
// Kernel 1: row squared-norms for z (BATCH rows) and centers (NC rows).
// f64 accumulation -> closer to exact than the reference's own f32 sums,
// which strictly reduces the chance of top-k selection swaps.
// ---------------------------------------------------------------------------
__global__ __launch_bounds__(128) void norms_kernel(const float* __restrict__ z,
                                                    const float* __restrict__ c,
                                                    float* __restrict__ z2,
                                                    float* __restrict__ c2) {
  int row = blockIdx.x;
  const float* src;
  float* dst;
  if (row < BATCH) { src = z + (size_t)row * DIM; dst = z2 + row; }
  else             { src = c + (size_t)(row - BATCH) * DIM; dst = c2 + (row - BATCH); }
  int t = threadIdx.x;                       // 128 threads, DIM/4 = 128 float4
  float4 v = ((const float4*)src)[t];
  double acc = (double)v.x * v.x + (double)v.y * v.y + (double)v.z * v.z + (double)v.w * v.w;
#pragma unroll
  for (int off = 32; off > 0; off >>= 1) acc += __shfl_down(acc, off);
  __shared__ double wsum[2];
  if ((t & 63) == 0) wsum[t >> 6] = acc;
  __syncthreads();
  if (t == 0) *dst = (float)(wsum[0] + wsum[1]);
}

// ---------------------------------------------------------------------------
// Kernel 2: attractions = mus / (dist^2 + 1e-6), dist via GEMM-style sq.
// f32 vector SGEMM, 128x128 tile, BK=32, 256 threads, 8x8 micro-tile.
// Epilogue replicates the reference's exact f32 rounding sequence.
// ---------------------------------------------------------------------------
#define BM 128
#define BN 128
#define BK 32

__global__ __launch_bounds__(256) void attr_kernel(const float* __restrict__ A,
                                                   const float* __restrict__ Bc,
                                                   const float* __restrict__ z2,
                                                   const float* __restrict__ c2,
                                                   const float* __restrict__ mus,
                                                   float* __restrict__ att) {
  __shared__ float As[BK][BM + 4];
  __shared__ float Bs[BK][BN + 4];
  const int tid = threadIdx.x;
  const int tx = tid & 15;   // 0..15  -> cols tx*4 .. +4 and 64+tx*4 .. +4
  const int ty = tid >> 4;   // 0..15  -> rows ty*8 .. +8
  const int row0 = blockIdx.y * BM;
  const int col0 = blockIdx.x * BN;
  const int lr = tid >> 3;          // 0..31 (row within load group)
  const int lc = (tid & 7) << 2;    // 0,4,...,28 (k-col, float4 granular)

  float acc[8][8];
#pragma unroll
  for (int i = 0; i < 8; ++i)
#pragma unroll
    for (int j = 0; j < 8; ++j) acc[i][j] = 0.0f;

  const float* Ag = A + (size_t)row0 * DIM;
  const float* Bg = Bc + (size_t)col0 * DIM;

  for (int k0 = 0; k0 < DIM; k0 += BK) {
#pragma unroll
    for (int p = 0; p < 4; ++p) {
      int r = lr + p * 32;
      float4 va = *(const float4*)(Ag + (size_t)r * DIM + k0 + lc);
      As[lc + 0][r] = va.x; As[lc + 1][r] = va.y;
      As[lc + 2][r] = va.z; As[lc + 3][r] = va.w;
      float4 vb = *(const float4*)(Bg + (size_t)r * DIM + k0 + lc);
      Bs[lc + 0][r] = vb.x; Bs[lc + 1][r] = vb.y;
      Bs[lc + 2][r] = vb.z; Bs[lc + 3][r] = vb.w;
    }
    __syncthreads();
#pragma unroll 8
    for (int k = 0; k < BK; ++k) {
      float a[8], b[8];
      *(float4*)&a[0] = *(const float4*)&As[k][ty * 8];
      *(float4*)&a[4] = *(const float4*)&As[k][ty * 8 + 4];
      *(float4*)&b[0] = *(const float4*)&Bs[k][tx * 4];
      *(float4*)&b[4] = *(const float4*)&Bs[k][tx * 4 + 64];
#pragma unroll
      for (int i = 0; i < 8; ++i)
#pragma unroll
        for (int j = 0; j < 8; ++j) acc[i][j] = fmaf(a[i], b[j], acc[i][j]);
    }
    __syncthreads();
  }

  // Epilogue: sq = (z2 + c2) - 2*dot ; d = sqrt(max(sq,0)) ; att = mu/(d*d + 1e-6)
  // Explicit __f*_rn ops to forbid FMA contraction (match reference rounding).
#pragma unroll
  for (int i = 0; i < 8; ++i) {
    int gr = row0 + ty * 8 + i;
    float zz = z2[gr];
    float o[8];
#pragma unroll
    for (int j = 0; j < 8; ++j) {
      int gc = col0 + ((j < 4) ? (tx * 4 + j) : (64 + tx * 4 + (j - 4)));
      float t  = __fadd_rn(zz, c2[gc]);
      float sq = __fsub_rn(t, __fmul_rn(2.0f, acc[i][j]));
      float d  = sqrtf(fmaxf(sq, 0.0f));
      float den = __fadd_rn(__fmul_rn(d, d), 1e-6f);
      o[j] = __fdiv_rn(mus[gc], den);
    }
    float* dst = att + (size_t)gr * NC + col0;
    *(float4*)(dst + tx * 4)      = *(float4*)&o[0];
    *(float4*)(dst + 64 + tx * 4) = *(float4*)&o[4];
  }
}

// ---------------------------------------------------------------------------
// Kernel 3: per-row top-5 (jax.lax.top_k tie-break: lower index wins),
// softmax over the 5 values, gather centers, expanded = 0.7*z + 0.3*comb.
// One 256-thread block per row; row staged in LDS (32 KB).
// ---------------------------------------------------------------------------
__global__ __launch_bounds__(256) void topk_kernel(const float* __restrict__ att,
                                                   const float* __restrict__ z,
                                                   const float* __restrict__ centers,
                                                   float* __restrict__ out) {
  __shared__ float sA[NC];
  __shared__ float rv[4];
  __shared__ int   ri[4];
  __shared__ float selv_s;
  __shared__ int   seli_s;

  const int row = blockIdx.x;
  const int tid = threadIdx.x;
  const float* arow = att + (size_t)row * NC;

#pragma unroll
  for (int p = 0; p < NC / 4 / 256; ++p)   // 8 float4 per thread
    ((float4*)sA)[tid + p * 256] = ((const float4*)arow)[tid + p * 256];
  __syncthreads();

  float topv[KEXP];
  int   topi[KEXP];
  for (int it = 0; it < KEXP; ++it) {
    float bv = -INFINITY;
    int   bi = NC;
    for (int j = tid; j < NC; j += 256) {
      float v = sA[j];
      if (v > bv) { bv = v; bi = j; }      // ascending j: '>' keeps lowest index on ties
    }
#pragma unroll
    for (int off = 32; off > 0; off >>= 1) {
      float ov = __shfl_down(bv, off);
      int   oi = __shfl_down(bi, off);
      if (ov > bv || (ov == bv && oi < bi)) { bv = ov; bi = oi; }
    }
    if ((tid & 63) == 0) { rv[tid >> 6] = bv; ri[tid >> 6] = bi; }
    __syncthreads();
    if (tid == 0) {
      float fv = rv[0]; int fi = ri[0];
#pragma unroll
      for (int w = 1; w < 4; ++w)
        if (rv[w] > fv || (rv[w] == fv && ri[w] < fi)) { fv = rv[w]; fi = ri[w]; }
      selv_s = fv; seli_s = fi;
      sA[fi] = -INFINITY;                  // mask winner for next pass
    }
    __syncthreads();
    topv[it] = selv_s;
    topi[it] = seli_s;
  }

  // softmax over the 5 selected values (topv[0] is the max by construction)
  float m = topv[0];
  float w[KEXP];
  float s = 0.0f;
#pragma unroll
  for (int k = 0; k < KEXP; ++k) { w[k] = expf(topv[k] - m); s += w[k]; }
#pragma unroll
  for (int k = 0; k < KEXP; ++k) w[k] /= s;

  // expanded = 0.7*z + 0.3 * sum_k w[k]*centers[topi[k]]
  for (int d0 = tid; d0 < DIM; d0 += 256) {
    float comb = 0.0f;
#pragma unroll
    for (int k = 0; k < KEXP; ++k)
      comb += w[k] * centers[(size_t)topi[k] * DIM + d0];
    float res = __fadd_rn(__fmul_rn(0.7f, z[(size_t)row * DIM + d0]),
                          __fmul_rn(0.3f, comb));
    out[(size_t)row * DIM + d0] = res;
  }
}

// ---------------------------------------------------------------------------
extern "C" void kernel_launch(void* const* d_in, const int* in_sizes, int n_in,
                              void* d_out, int out_size, void* d_ws, size_t ws_size,
                              hipStream_t stream) {
  const float* z       = (const float*)d_in[0];
  const float* centers = (const float*)d_in[1];
  const float* mus     = (const float*)d_in[2];
  float* out      = (float*)d_out;
  float* expanded = out;                                 // BATCH*DIM
  float* att      = out + (size_t)BATCH * DIM;           // BATCH*NC
  float* z2 = (float*)d_ws;                              // BATCH floats
  float* c2 = z2 + BATCH;                                // NC floats (48 KB total)

  norms_kernel<<<BATCH + NC, 128, 0, stream>>>(z, centers, z2, c2);
  dim3 grid(NC / BN, BATCH / BM);
  attr_kernel<<<grid, 256, 0, stream>>>(z, centers, z2, c2, mus, att);
  topk_kernel<<<BATCH, 256, 0, stream>>>(att, z, centers, expanded);
}

// Round 3
// 289.949 us; speedup vs baseline: 1.6936x; 1.6936x over previous
//
#include <hip/hip_runtime.h>
#include <math.h>

#define BATCH 4096
#define NC    8192
#define DIM   512
#define KEXP  5
#define NCAND 10

using bf16x8 = __attribute__((ext_vector_type(8))) short;
using f32x4  = __attribute__((ext_vector_type(4))) float;

// module-scope device buffers (no hipMalloc; deterministic, rewritten every call)
__device__ unsigned short g_zbf[BATCH * DIM];   // 4 MB bf16(z)
__device__ unsigned short g_cbf[NC * DIM];      // 8 MB bf16(centers)
__device__ float g_z2[BATCH];
__device__ float g_c2[NC];

__device__ __forceinline__ unsigned short rtne_bf16(float f) {
  unsigned u = __float_as_uint(f);
  u += 0x7FFFu + ((u >> 16) & 1u);
  return (unsigned short)(u >> 16);
}

__device__ __forceinline__ void gload16(const void* g, void* l) {
  __builtin_amdgcn_global_load_lds(
      (const __attribute__((address_space(1))) void*)g,
      (__attribute__((address_space(3))) void*)l, 16, 0, 0);
}

// ---------------------------------------------------------------------------
// Kernel 0: f32 -> bf16 (RTN) one-shot conversion of z and centers.
// ---------------------------------------------------------------------------
__global__ __launch_bounds__(256) void convert_kernel(const float* __restrict__ z,
                                                      const float* __restrict__ c) {
  const size_t i = ((size_t)blockIdx.x * 256 + threadIdx.x) * 8;
  const size_t zn = (size_t)BATCH * DIM;
  const float* src;
  unsigned short* dst;
  size_t off;
  if (i < zn) { src = z; dst = g_zbf; off = i; }
  else        { src = c; dst = g_cbf; off = i - zn; }
  float4 a = *(const float4*)(src + off);
  float4 b = *(const float4*)(src + off + 4);
  uint4 o;
  o.x = (unsigned)rtne_bf16(a.x) | ((unsigned)rtne_bf16(a.y) << 16);
  o.y = (unsigned)rtne_bf16(a.z) | ((unsigned)rtne_bf16(a.w) << 16);
  o.z = (unsigned)rtne_bf16(b.x) | ((unsigned)rtne_bf16(b.y) << 16);
  o.w = (unsigned)rtne_bf16(b.z) | ((unsigned)rtne_bf16(b.w) << 16);
  *(uint4*)(dst + off) = o;
}

// ---------------------------------------------------------------------------
// Kernel 1: row squared-norms, f64 accumulation.
// ---------------------------------------------------------------------------
__global__ __launch_bounds__(128) void norms_kernel(const float* __restrict__ z,
                                                    const float* __restrict__ c) {
  int row = blockIdx.x;
  const float* src;
  float* dst;
  if (row < BATCH) { src = z + (size_t)row * DIM; dst = g_z2 + row; }
  else             { src = c + (size_t)(row - BATCH) * DIM; dst = g_c2 + (row - BATCH); }
  int t = threadIdx.x;
  float4 v = ((const float4*)src)[t];
  double acc = (double)v.x * v.x + (double)v.y * v.y + (double)v.z * v.z + (double)v.w * v.w;
#pragma unroll
  for (int off = 32; off > 0; off >>= 1) acc += __shfl_down(acc, off);
  __shared__ double wsum[2];
  if ((t & 63) == 0) wsum[t >> 6] = acc;
  __syncthreads();
  if (t == 0) *dst = (float)(wsum[0] + wsum[1]);
}

// ---------------------------------------------------------------------------
// Kernel 2: attractions via single-term bf16 MFMA GEMM.
// 128x128 tile, BK=64, 256 thr = 2x2 waves, 4x4 frags of 16x16x32.
// LDS [128][64] bf16, XOR swizzle granule ^= row&7; staged with
// global_load_lds(16B) from pre-swizzled global source (linear LDS dest).
// ---------------------------------------------------------------------------
#define BM  128
#define BN  128
#define BKK 64

__global__ __launch_bounds__(256) void attr_bf16(const float* __restrict__ mus,
                                                 float* __restrict__ att) {
  __shared__ __align__(16) unsigned short Ah[BM * BKK];  // 16 KB
  __shared__ __align__(16) unsigned short Bh[BM * BKK];  // 16 KB

  const int tid  = threadIdx.x;
  const int lane = tid & 63;
  const int wid  = tid >> 6;
  const int wm   = wid >> 1;
  const int wn   = wid & 1;

  // XCD-aware swizzle of flat block id (2048 blocks, 2048%8==0 -> bijective)
  const int flat = blockIdx.y * gridDim.x + blockIdx.x;
  const int swz  = (flat & 7) * 256 + (flat >> 3);
  const int col0 = (swz & 63) * BN;
  const int row0 = (swz >> 6) * BM;

  f32x4 acc[4][4] = {};

  const unsigned short* Ag = g_zbf + (size_t)row0 * DIM;
  const unsigned short* Bg = g_cbf + (size_t)col0 * DIM;

  // staging: wave w stages rows [w*32, w*32+32) in 4 chunks of 8 rows.
  // lane l -> row = base+ (l>>3), granule (l&7); source pre-swizzled.
  const int crow = lane >> 3;
  const int gsw  = (lane & 7) ^ crow;   // cgr ^ (row&7), row&7==crow

  for (int k0 = 0; k0 < DIM; k0 += BKK) {
#pragma unroll
    for (int j = 0; j < 4; ++j) {
      const int base_row = (wid * 4 + j) * 8;
      const int r = base_row + crow;
      gload16(Ag + (size_t)r * DIM + k0 + gsw * 8, Ah + base_row * 64);
      gload16(Bg + (size_t)r * DIM + k0 + gsw * 8, Bh + base_row * 64);
    }
    __syncthreads();

#pragma unroll
    for (int kk = 0; kk < 2; ++kk) {
      bf16x8 fa[4], fb[4];
#pragma unroll
      for (int i = 0; i < 4; ++i) {
        const int r = wm * 64 + i * 16 + (lane & 15);
        const int g = (kk * 4 + (lane >> 4)) ^ (r & 7);
        fa[i] = *(const bf16x8*)((const char*)Ah + r * 128 + g * 16);
      }
#pragma unroll
      for (int j2 = 0; j2 < 4; ++j2) {
        const int r = wn * 64 + j2 * 16 + (lane & 15);
        const int g = (kk * 4 + (lane >> 4)) ^ (r & 7);
        fb[j2] = *(const bf16x8*)((const char*)Bh + r * 128 + g * 16);
      }
#pragma unroll
      for (int i = 0; i < 4; ++i)
#pragma unroll
        for (int j2 = 0; j2 < 4; ++j2)
          acc[i][j2] = __builtin_amdgcn_mfma_f32_16x16x32_bf16(fa[i], fb[j2], acc[i][j2], 0, 0, 0);
    }
    __syncthreads();
  }

  // epilogue: reference's f32 rounding sequence
#pragma unroll
  for (int i = 0; i < 4; ++i) {
    const int mrow = row0 + wm * 64 + i * 16 + (lane >> 4) * 4;
    float zz[4];
#pragma unroll
    for (int r = 0; r < 4; ++r) zz[r] = g_z2[mrow + r];
#pragma unroll
    for (int j = 0; j < 4; ++j) {
      const int gc = col0 + wn * 64 + j * 16 + (lane & 15);
      const float cc = g_c2[gc];
      const float mu = mus[gc];
#pragma unroll
      for (int r = 0; r < 4; ++r) {
        float t   = __fadd_rn(zz[r], cc);
        float sq  = __fsub_rn(t, __fmul_rn(2.0f, acc[i][j][r]));
        float d   = sqrtf(fmaxf(sq, 0.0f));
        float den = __fadd_rn(__fmul_rn(d, d), 1e-6f);
        att[(size_t)(mrow + r) * NC + gc] = __fdiv_rn(mu, den);
      }
    }
  }
}

// ---------------------------------------------------------------------------
// Kernel 3: top-NCAND by bf16 attraction -> exact f64-dot re-rank -> top-5
// softmax -> gather-combine. Selection thus immune to bf16 GEMM noise.
// ---------------------------------------------------------------------------
__global__ __launch_bounds__(256) void topk_kernel(const float* __restrict__ att,
                                                   const float* __restrict__ z,
                                                   const float* __restrict__ centers,
                                                   const float* __restrict__ mus,
                                                   float* __restrict__ out) {
  __shared__ float sA[NC];        // 32 KB
  __shared__ float rv[4];
  __shared__ int   ri[4];
  __shared__ int   seli_s;
  __shared__ double dpart[4];
  __shared__ float cex[NCAND];
  __shared__ int   cidx[NCAND];

  const int row = blockIdx.x;
  const int tid = threadIdx.x;
  const float* arow = att + (size_t)row * NC;

#pragma unroll
  for (int p = 0; p < NC / 4 / 256; ++p)
    ((float4*)sA)[tid + p * 256] = ((const float4*)arow)[tid + p * 256];
  __syncthreads();

  // --- NCAND iterative argmax passes (jax tie-break: lower index wins) ---
  for (int it = 0; it < NCAND; ++it) {
    float bv = -INFINITY;
    int   bi = NC;
    for (int j = tid; j < NC; j += 256) {
      float v = sA[j];
      if (v > bv) { bv = v; bi = j; }
    }
#pragma unroll
    for (int off = 32; off > 0; off >>= 1) {
      float ov = __shfl_down(bv, off);
      int   oi = __shfl_down(bi, off);
      if (ov > bv || (ov == bv && oi < bi)) { bv = ov; bi = oi; }
    }
    if ((tid & 63) == 0) { rv[tid >> 6] = bv; ri[tid >> 6] = bi; }
    __syncthreads();
    if (tid == 0) {
      float fv = rv[0]; int fi = ri[0];
#pragma unroll
      for (int w = 1; w < 4; ++w)
        if (rv[w] > fv || (rv[w] == fv && ri[w] < fi)) { fv = rv[w]; fi = ri[w]; }
      cidx[it] = fi;
      sA[fi] = -INFINITY;
      seli_s = fi;
    }
    __syncthreads();
  }

  // --- exact re-computation of the NCAND candidates (f64 dot) ---
  const float* zrow = z + (size_t)row * DIM;
  for (int cc = 0; cc < NCAND; ++cc) {
    const float* crow_p = centers + (size_t)cidx[cc] * DIM;
    double p = 0.0;
    for (int d = tid; d < DIM; d += 256)
      p += (double)zrow[d] * (double)crow_p[d];
#pragma unroll
    for (int off = 32; off > 0; off >>= 1) p += __shfl_down(p, off);
    if ((tid & 63) == 0) dpart[tid >> 6] = p;
    __syncthreads();
    if (tid == 0) {
      float dotf = (float)(dpart[0] + dpart[1] + dpart[2] + dpart[3]);
      int ci = cidx[cc];
      float t   = __fadd_rn(g_z2[row], g_c2[ci]);
      float sq  = __fsub_rn(t, __fmul_rn(2.0f, dotf));
      float d1  = sqrtf(fmaxf(sq, 0.0f));
      float den = __fadd_rn(__fmul_rn(d1, d1), 1e-6f);
      cex[cc] = __fdiv_rn(mus[ci], den);
    }
    __syncthreads();
  }

  // --- redundant per-thread re-rank of NCAND by (value desc, index asc) ---
  float ev[NCAND]; int ei[NCAND]; bool used[NCAND];
#pragma unroll
  for (int c = 0; c < NCAND; ++c) { ev[c] = cex[c]; ei[c] = cidx[c]; used[c] = false; }
  float tv[KEXP]; int tix[KEXP];
#pragma unroll
  for (int s = 0; s < KEXP; ++s) {
    int best = -1;
#pragma unroll
    for (int c = 0; c < NCAND; ++c) {
      if (used[c]) continue;
      if (best < 0 || ev[c] > ev[best] || (ev[c] == ev[best] && ei[c] < ei[best])) best = c;
    }
    used[best] = true; tv[s] = ev[best]; tix[s] = ei[best];
  }

  // softmax over the 5 exact values (tv[0] is the max)
  float m = tv[0];
  float w[KEXP];
  float s = 0.0f;
#pragma unroll
  for (int k = 0; k < KEXP; ++k) { w[k] = expf(tv[k] - m); s += w[k]; }
#pragma unroll
  for (int k = 0; k < KEXP; ++k) w[k] /= s;

  for (int d0 = tid; d0 < DIM; d0 += 256) {
    float comb = 0.0f;
#pragma unroll
    for (int k = 0; k < KEXP; ++k)
      comb += w[k] * centers[(size_t)tix[k] * DIM + d0];
    float res = __fadd_rn(__fmul_rn(0.7f, zrow[d0]),
                          __fmul_rn(0.3f, comb));
    out[(size_t)row * DIM + d0] = res;
  }
}

// ---------------------------------------------------------------------------
extern "C" void kernel_launch(void* const* d_in, const int* in_sizes, int n_in,
                              void* d_out, int out_size, void* d_ws, size_t ws_size,
                              hipStream_t stream) {
  const float* z       = (const float*)d_in[0];
  const float* centers = (const float*)d_in[1];
  const float* mus     = (const float*)d_in[2];
  float* out      = (float*)d_out;
  float* expanded = out;
  float* att      = out + (size_t)BATCH * DIM;

  convert_kernel<<<(BATCH + NC) * DIM / (256 * 8), 256, 0, stream>>>(z, centers);
  norms_kernel<<<BATCH + NC, 128, 0, stream>>>(z, centers);
  dim3 grid(NC / BN, BATCH / BM);
  attr_bf16<<<grid, 256, 0, stream>>>(mus, att);
  topk_kernel<<<BATCH, 256, 0, stream>>>(att, z, centers, mus, expanded);
}

// Round 4
// 179.948 us; speedup vs baseline: 2.7289x; 1.6113x over previous
//
#include <hip/hip_runtime.h>
#include <math.h>

#define BATCH 4096
#define NC    8192
#define DIM   512
#define KEXP  5
#define NCAND 10

using bf16x8 = __attribute__((ext_vector_type(8))) short;
using f32x4  = __attribute__((ext_vector_type(4))) float;

// module-scope device buffers (no hipMalloc; deterministic, rewritten every call)
__device__ unsigned short g_zbf[BATCH * DIM];   // 4 MB bf16(z)
__device__ unsigned short g_cbf[NC * DIM];      // 8 MB bf16(centers)
__device__ float g_z2[BATCH];
__device__ float g_c2[NC];

__device__ __forceinline__ unsigned short rtne_bf16(float f) {
  unsigned u = __float_as_uint(f);
  u += 0x7FFFu + ((u >> 16) & 1u);
  return (unsigned short)(u >> 16);
}

__device__ __forceinline__ void gload16(const void* g, void* l) {
  __builtin_amdgcn_global_load_lds(
      (const __attribute__((address_space(1))) void*)g,
      (__attribute__((address_space(3))) void*)l, 16, 0, 0);
}

// ---------------------------------------------------------------------------
// Kernel 0: f32 -> bf16 (RTN) one-shot conversion of z and centers.
// ---------------------------------------------------------------------------
__global__ __launch_bounds__(256) void convert_kernel(const float* __restrict__ z,
                                                      const float* __restrict__ c) {
  const size_t i = ((size_t)blockIdx.x * 256 + threadIdx.x) * 8;
  const size_t zn = (size_t)BATCH * DIM;
  const float* src;
  unsigned short* dst;
  size_t off;
  if (i < zn) { src = z; dst = g_zbf; off = i; }
  else        { src = c; dst = g_cbf; off = i - zn; }
  float4 a = *(const float4*)(src + off);
  float4 b = *(const float4*)(src + off + 4);
  uint4 o;
  o.x = (unsigned)rtne_bf16(a.x) | ((unsigned)rtne_bf16(a.y) << 16);
  o.y = (unsigned)rtne_bf16(a.z) | ((unsigned)rtne_bf16(a.w) << 16);
  o.z = (unsigned)rtne_bf16(b.x) | ((unsigned)rtne_bf16(b.y) << 16);
  o.w = (unsigned)rtne_bf16(b.z) | ((unsigned)rtne_bf16(b.w) << 16);
  *(uint4*)(dst + off) = o;
}

// ---------------------------------------------------------------------------
// Kernel 1: row squared-norms, f64 accumulation.
// ---------------------------------------------------------------------------
__global__ __launch_bounds__(128) void norms_kernel(const float* __restrict__ z,
                                                    const float* __restrict__ c) {
  int row = blockIdx.x;
  const float* src;
  float* dst;
  if (row < BATCH) { src = z + (size_t)row * DIM; dst = g_z2 + row; }
  else             { src = c + (size_t)(row - BATCH) * DIM; dst = g_c2 + (row - BATCH); }
  int t = threadIdx.x;
  float4 v = ((const float4*)src)[t];
  double acc = (double)v.x * v.x + (double)v.y * v.y + (double)v.z * v.z + (double)v.w * v.w;
#pragma unroll
  for (int off = 32; off > 0; off >>= 1) acc += __shfl_down(acc, off);
  __shared__ double wsum[2];
  if ((t & 63) == 0) wsum[t >> 6] = acc;
  __syncthreads();
  if (t == 0) *dst = (float)(wsum[0] + wsum[1]);
}

// ---------------------------------------------------------------------------
// Kernel 2: attractions via single-term bf16 MFMA GEMM (unchanged, verified).
// ---------------------------------------------------------------------------
#define BM  128
#define BN  128
#define BKK 64

__global__ __launch_bounds__(256) void attr_bf16(const float* __restrict__ mus,
                                                 float* __restrict__ att) {
  __shared__ __align__(16) unsigned short Ah[BM * BKK];
  __shared__ __align__(16) unsigned short Bh[BM * BKK];

  const int tid  = threadIdx.x;
  const int lane = tid & 63;
  const int wid  = tid >> 6;
  const int wm   = wid >> 1;
  const int wn   = wid & 1;

  const int flat = blockIdx.y * gridDim.x + blockIdx.x;
  const int swz  = (flat & 7) * 256 + (flat >> 3);
  const int col0 = (swz & 63) * BN;
  const int row0 = (swz >> 6) * BM;

  f32x4 acc[4][4] = {};

  const unsigned short* Ag = g_zbf + (size_t)row0 * DIM;
  const unsigned short* Bg = g_cbf + (size_t)col0 * DIM;

  const int crow = lane >> 3;
  const int gsw  = (lane & 7) ^ crow;

  for (int k0 = 0; k0 < DIM; k0 += BKK) {
#pragma unroll
    for (int j = 0; j < 4; ++j) {
      const int base_row = (wid * 4 + j) * 8;
      const int r = base_row + crow;
      gload16(Ag + (size_t)r * DIM + k0 + gsw * 8, Ah + base_row * 64);
      gload16(Bg + (size_t)r * DIM + k0 + gsw * 8, Bh + base_row * 64);
    }
    __syncthreads();

#pragma unroll
    for (int kk = 0; kk < 2; ++kk) {
      bf16x8 fa[4], fb[4];
#pragma unroll
      for (int i = 0; i < 4; ++i) {
        const int r = wm * 64 + i * 16 + (lane & 15);
        const int g = (kk * 4 + (lane >> 4)) ^ (r & 7);
        fa[i] = *(const bf16x8*)((const char*)Ah + r * 128 + g * 16);
      }
#pragma unroll
      for (int j2 = 0; j2 < 4; ++j2) {
        const int r = wn * 64 + j2 * 16 + (lane & 15);
        const int g = (kk * 4 + (lane >> 4)) ^ (r & 7);
        fb[j2] = *(const bf16x8*)((const char*)Bh + r * 128 + g * 16);
      }
#pragma unroll
      for (int i = 0; i < 4; ++i)
#pragma unroll
        for (int j2 = 0; j2 < 4; ++j2)
          acc[i][j2] = __builtin_amdgcn_mfma_f32_16x16x32_bf16(fa[i], fb[j2], acc[i][j2], 0, 0, 0);
    }
    __syncthreads();
  }

#pragma unroll
  for (int i = 0; i < 4; ++i) {
    const int mrow = row0 + wm * 64 + i * 16 + (lane >> 4) * 4;
    float zz[4];
#pragma unroll
    for (int r = 0; r < 4; ++r) zz[r] = g_z2[mrow + r];
#pragma unroll
    for (int j = 0; j < 4; ++j) {
      const int gc = col0 + wn * 64 + j * 16 + (lane & 15);
      const float cc = g_c2[gc];
      const float mu = mus[gc];
#pragma unroll
      for (int r = 0; r < 4; ++r) {
        float t   = __fadd_rn(zz[r], cc);
        float sq  = __fsub_rn(t, __fmul_rn(2.0f, acc[i][j][r]));
        float d   = sqrtf(fmaxf(sq, 0.0f));
        float den = __fadd_rn(__fmul_rn(d, d), 1e-6f);
        att[(size_t)(mrow + r) * NC + gc] = __fdiv_rn(mu, den);
      }
    }
  }
}

// ---------------------------------------------------------------------------
// Kernel 3: wave-per-row top-NCAND (barrier-free) -> exact f64 re-rank ->
// softmax -> gather-combine.
// Per lane: 8 chunk-maxima registers (16-elem chunks); per selection round:
// static chunk tree + 6-step shfl_xor butterfly; only the owning lane
// re-scans its 16-element chunk (skip-list repair). All indices static.
// ---------------------------------------------------------------------------
__global__ __launch_bounds__(256) void topk_kernel(const float* __restrict__ att,
                                                   const float* __restrict__ z,
                                                   const float* __restrict__ centers,
                                                   const float* __restrict__ mus,
                                                   float* __restrict__ out) {
  const int lane = threadIdx.x & 63;
  const int row  = blockIdx.x * 4 + (threadIdx.x >> 6);
  const float* arow = att + (size_t)row * NC;

  // ---- pass 1: per-lane chunk maxima (ascending idx, '>' keeps lowest) ----
  float cmv[8]; int cmi[8];
#pragma unroll
  for (int c = 0; c < 8; ++c) {
    float bv = -INFINITY; int bi = 0x7FFFFFFF;
    const int base = c * 1024 + lane * 16;
#pragma unroll
    for (int q = 0; q < 4; ++q) {
      float4 v = *(const float4*)(arow + base + q * 4);
      const int ib = base + q * 4;
      if (v.x > bv) { bv = v.x; bi = ib + 0; }
      if (v.y > bv) { bv = v.y; bi = ib + 1; }
      if (v.z > bv) { bv = v.z; bi = ib + 2; }
      if (v.w > bv) { bv = v.w; bi = ib + 3; }
    }
    cmv[c] = bv; cmi[c] = bi;
  }

  int   selIdx[NCAND];
  float selVal[NCAND];
#pragma unroll
  for (int s = 0; s < NCAND; ++s) selIdx[s] = -1;

#pragma unroll
  for (int it = 0; it < NCAND; ++it) {
    float v = cmv[0]; int i = cmi[0];
#pragma unroll
    for (int c = 1; c < 8; ++c)
      if (cmv[c] > v || (cmv[c] == v && cmi[c] < i)) { v = cmv[c]; i = cmi[c]; }
#pragma unroll
    for (int off = 32; off > 0; off >>= 1) {
      float ov = __shfl_xor(v, off);
      int   oi = __shfl_xor(i, off);
      if (ov > v || (ov == v && oi < i)) { v = ov; i = oi; }
    }
    selVal[it] = v; selIdx[it] = i;

    // owning lane repairs its chunk max (skip already-selected indices)
    const int ol = (i >> 4) & 63;
    const int oc = i >> 10;
    if (lane == ol) {
      float nv = -INFINITY; int ni = 0x7FFFFFFF;
      const int base = oc * 1024 + lane * 16;
#pragma unroll
      for (int q = 0; q < 4; ++q) {
        float4 v4 = *(const float4*)(arow + base + q * 4);
        float vv[4] = {v4.x, v4.y, v4.z, v4.w};
#pragma unroll
        for (int e = 0; e < 4; ++e) {
          const int idx = base + q * 4 + e;
          bool skip = false;
#pragma unroll
          for (int s = 0; s < NCAND; ++s) skip |= (idx == selIdx[s]);
          if (!skip && vv[e] > nv) { nv = vv[e]; ni = idx; }
        }
      }
#pragma unroll
      for (int c = 0; c < 8; ++c) if (c == oc) { cmv[c] = nv; cmi[c] = ni; }
    }
  }

  // ---- exact f64 re-computation of the NCAND candidates ----
  const float* zrow = z + (size_t)row * DIM;
  const int d0 = lane * 8;
  const float4 za = *(const float4*)(zrow + d0);
  const float4 zb = *(const float4*)(zrow + d0 + 4);
  const float myz2 = g_z2[row];

  float exv[NCAND];
#pragma unroll
  for (int c = 0; c < NCAND; ++c) {
    const int ci = selIdx[c];
    const float* cp = centers + (size_t)ci * DIM + d0;
    float4 ca = *(const float4*)(cp);
    float4 cb = *(const float4*)(cp + 4);
    double p = (double)za.x * ca.x + (double)za.y * ca.y +
               (double)za.z * ca.z + (double)za.w * ca.w +
               (double)zb.x * cb.x + (double)zb.y * cb.y +
               (double)zb.z * cb.z + (double)zb.w * cb.w;
#pragma unroll
    for (int off = 32; off > 0; off >>= 1) p += __shfl_xor(p, off);
    float dotf = (float)p;
    float t   = __fadd_rn(myz2, g_c2[ci]);
    float sq  = __fsub_rn(t, __fmul_rn(2.0f, dotf));
    float d   = sqrtf(fmaxf(sq, 0.0f));
    float den = __fadd_rn(__fmul_rn(d, d), 1e-6f);
    exv[c] = __fdiv_rn(mus[ci], den);
  }

  // ---- re-rank NCAND by (exact value desc, index asc), take top-5 ----
  bool used[NCAND];
#pragma unroll
  for (int c = 0; c < NCAND; ++c) used[c] = false;
  float tv[KEXP]; int tix[KEXP];
#pragma unroll
  for (int s = 0; s < KEXP; ++s) {
    float bv = -INFINITY; int bi = 0x7FFFFFFF; int bc = 0;
#pragma unroll
    for (int c = 0; c < NCAND; ++c) {
      if (!used[c] && (exv[c] > bv || (exv[c] == bv && selIdx[c] < bi))) {
        bv = exv[c]; bi = selIdx[c]; bc = c;
      }
    }
#pragma unroll
    for (int c = 0; c < NCAND; ++c) if (c == bc) used[c] = true;
    tv[s] = bv; tix[s] = bi;
  }

  // ---- softmax over the 5 exact values (tv[0] is the max) ----
  float m = tv[0];
  float w[KEXP];
  float s = 0.0f;
#pragma unroll
  for (int k = 0; k < KEXP; ++k) { w[k] = expf(tv[k] - m); s += w[k]; }
#pragma unroll
  for (int k = 0; k < KEXP; ++k) w[k] /= s;

  // ---- combine: out = 0.7*z + 0.3*sum_k w[k]*centers[tix[k]] ----
  float comb[8] = {0, 0, 0, 0, 0, 0, 0, 0};
#pragma unroll
  for (int k = 0; k < KEXP; ++k) {
    const float* cp = centers + (size_t)tix[k] * DIM + d0;
    float4 a = *(const float4*)(cp);
    float4 b = *(const float4*)(cp + 4);
    comb[0] += w[k] * a.x; comb[1] += w[k] * a.y;
    comb[2] += w[k] * a.z; comb[3] += w[k] * a.w;
    comb[4] += w[k] * b.x; comb[5] += w[k] * b.y;
    comb[6] += w[k] * b.z; comb[7] += w[k] * b.w;
  }
  const float zv[8] = {za.x, za.y, za.z, za.w, zb.x, zb.y, zb.z, zb.w};
  float o[8];
#pragma unroll
  for (int e = 0; e < 8; ++e)
    o[e] = __fadd_rn(__fmul_rn(0.7f, zv[e]), __fmul_rn(0.3f, comb[e]));
  *(float4*)(out + (size_t)row * DIM + d0)     = *(float4*)&o[0];
  *(float4*)(out + (size_t)row * DIM + d0 + 4) = *(float4*)&o[4];
}

// ---------------------------------------------------------------------------
extern "C" void kernel_launch(void* const* d_in, const int* in_sizes, int n_in,
                              void* d_out, int out_size, void* d_ws, size_t ws_size,
                              hipStream_t stream) {
  const float* z       = (const float*)d_in[0];
  const float* centers = (const float*)d_in[1];
  const float* mus     = (const float*)d_in[2];
  float* out      = (float*)d_out;
  float* expanded = out;
  float* att      = out + (size_t)BATCH * DIM;

  convert_kernel<<<(BATCH + NC) * DIM / (256 * 8), 256, 0, stream>>>(z, centers);
  norms_kernel<<<BATCH + NC, 128, 0, stream>>>(z, centers);
  dim3 grid(NC / BN, BATCH / BM);
  attr_bf16<<<grid, 256, 0, stream>>>(mus, att);
  topk_kernel<<<BATCH / 4, 256, 0, stream>>>(att, z, centers, mus, expanded);
}

// Round 5
// 172.359 us; speedup vs baseline: 2.8491x; 1.0440x over previous
//
#include <hip/hip_runtime.h>
#include <math.h>

#define BATCH 4096
#define NC    8192
#define DIM   512
#define KEXP  5
#define NCAND 10

using bf16x8 = __attribute__((ext_vector_type(8))) short;
using f32x4  = __attribute__((ext_vector_type(4))) float;

// module-scope device buffers (no hipMalloc; deterministic, rewritten every call)
__device__ unsigned short g_zbf[BATCH * DIM];   // 4 MB bf16(z)
__device__ unsigned short g_cbf[NC * DIM];      // 8 MB bf16(centers)
__device__ float g_z2[BATCH];
__device__ float g_c2[NC];

__device__ __forceinline__ unsigned short rtne_bf16(float f) {
  unsigned u = __float_as_uint(f);
  u += 0x7FFFu + ((u >> 16) & 1u);
  return (unsigned short)(u >> 16);
}

__device__ __forceinline__ void gload16(const void* g, void* l) {
  __builtin_amdgcn_global_load_lds(
      (const __attribute__((address_space(1))) void*)g,
      (__attribute__((address_space(3))) void*)l, 16, 0, 0);
}

// ---------------------------------------------------------------------------
// Kernel 0: f32 -> bf16 (RTN) one-shot conversion of z and centers.
// ---------------------------------------------------------------------------
__global__ __launch_bounds__(256) void convert_kernel(const float* __restrict__ z,
                                                      const float* __restrict__ c) {
  const size_t i = ((size_t)blockIdx.x * 256 + threadIdx.x) * 8;
  const size_t zn = (size_t)BATCH * DIM;
  const float* src;
  unsigned short* dst;
  size_t off;
  if (i < zn) { src = z; dst = g_zbf; off = i; }
  else        { src = c; dst = g_cbf; off = i - zn; }
  float4 a = *(const float4*)(src + off);
  float4 b = *(const float4*)(src + off + 4);
  uint4 o;
  o.x = (unsigned)rtne_bf16(a.x) | ((unsigned)rtne_bf16(a.y) << 16);
  o.y = (unsigned)rtne_bf16(a.z) | ((unsigned)rtne_bf16(a.w) << 16);
  o.z = (unsigned)rtne_bf16(b.x) | ((unsigned)rtne_bf16(b.y) << 16);
  o.w = (unsigned)rtne_bf16(b.z) | ((unsigned)rtne_bf16(b.w) << 16);
  *(uint4*)(dst + off) = o;
}

// ---------------------------------------------------------------------------
// Kernel 1: row squared-norms, f64 accumulation.
// ---------------------------------------------------------------------------
__global__ __launch_bounds__(128) void norms_kernel(const float* __restrict__ z,
                                                    const float* __restrict__ c) {
  int row = blockIdx.x;
  const float* src;
  float* dst;
  if (row < BATCH) { src = z + (size_t)row * DIM; dst = g_z2 + row; }
  else             { src = c + (size_t)(row - BATCH) * DIM; dst = g_c2 + (row - BATCH); }
  int t = threadIdx.x;
  float4 v = ((const float4*)src)[t];
  double acc = (double)v.x * v.x + (double)v.y * v.y + (double)v.z * v.z + (double)v.w * v.w;
#pragma unroll
  for (int off = 32; off > 0; off >>= 1) acc += __shfl_down(acc, off);
  __shared__ double wsum[2];
  if ((t & 63) == 0) wsum[t >> 6] = acc;
  __syncthreads();
  if (t == 0) *dst = (float)(wsum[0] + wsum[1]);
}

// ---------------------------------------------------------------------------
// Kernel 2: attractions via single-term bf16 MFMA GEMM (unchanged, verified).
// ---------------------------------------------------------------------------
#define BM  128
#define BN  128
#define BKK 64

__global__ __launch_bounds__(256) void attr_bf16(const float* __restrict__ mus,
                                                 float* __restrict__ att) {
  __shared__ __align__(16) unsigned short Ah[BM * BKK];
  __shared__ __align__(16) unsigned short Bh[BM * BKK];

  const int tid  = threadIdx.x;
  const int lane = tid & 63;
  const int wid  = tid >> 6;
  const int wm   = wid >> 1;
  const int wn   = wid & 1;

  const int flat = blockIdx.y * gridDim.x + blockIdx.x;
  const int swz  = (flat & 7) * 256 + (flat >> 3);
  const int col0 = (swz & 63) * BN;
  const int row0 = (swz >> 6) * BM;

  f32x4 acc[4][4] = {};

  const unsigned short* Ag = g_zbf + (size_t)row0 * DIM;
  const unsigned short* Bg = g_cbf + (size_t)col0 * DIM;

  const int crow = lane >> 3;
  const int gsw  = (lane & 7) ^ crow;

  for (int k0 = 0; k0 < DIM; k0 += BKK) {
#pragma unroll
    for (int j = 0; j < 4; ++j) {
      const int base_row = (wid * 4 + j) * 8;
      const int r = base_row + crow;
      gload16(Ag + (size_t)r * DIM + k0 + gsw * 8, Ah + base_row * 64);
      gload16(Bg + (size_t)r * DIM + k0 + gsw * 8, Bh + base_row * 64);
    }
    __syncthreads();

#pragma unroll
    for (int kk = 0; kk < 2; ++kk) {
      bf16x8 fa[4], fb[4];
#pragma unroll
      for (int i = 0; i < 4; ++i) {
        const int r = wm * 64 + i * 16 + (lane & 15);
        const int g = (kk * 4 + (lane >> 4)) ^ (r & 7);
        fa[i] = *(const bf16x8*)((const char*)Ah + r * 128 + g * 16);
      }
#pragma unroll
      for (int j2 = 0; j2 < 4; ++j2) {
        const int r = wn * 64 + j2 * 16 + (lane & 15);
        const int g = (kk * 4 + (lane >> 4)) ^ (r & 7);
        fb[j2] = *(const bf16x8*)((const char*)Bh + r * 128 + g * 16);
      }
#pragma unroll
      for (int i = 0; i < 4; ++i)
#pragma unroll
        for (int j2 = 0; j2 < 4; ++j2)
          acc[i][j2] = __builtin_amdgcn_mfma_f32_16x16x32_bf16(fa[i], fb[j2], acc[i][j2], 0, 0, 0);
    }
    __syncthreads();
  }

#pragma unroll
  for (int i = 0; i < 4; ++i) {
    const int mrow = row0 + wm * 64 + i * 16 + (lane >> 4) * 4;
    float zz[4];
#pragma unroll
    for (int r = 0; r < 4; ++r) zz[r] = g_z2[mrow + r];
#pragma unroll
    for (int j = 0; j < 4; ++j) {
      const int gc = col0 + wn * 64 + j * 16 + (lane & 15);
      const float cc = g_c2[gc];
      const float mu = mus[gc];
#pragma unroll
      for (int r = 0; r < 4; ++r) {
        float t   = __fadd_rn(zz[r], cc);
        float sq  = __fsub_rn(t, __fmul_rn(2.0f, acc[i][j][r]));
        float d   = sqrtf(fmaxf(sq, 0.0f));
        float den = __fadd_rn(__fmul_rn(d, d), 1e-6f);
        att[(size_t)(mrow + r) * NC + gc] = __fdiv_rn(mu, den);
      }
    }
  }
}

// ---------------------------------------------------------------------------
// Kernel 3: wave-per-row top-NCAND, COALESCED pass 1.
// Pass q of chunk c: lane l reads float4 index c*256 + q*64 + l (wave = 1 KB
// contiguous). Lane l owns elements c*1024 + q*256 + l*4 + e; visit order
// (q asc, e asc) is index-ascending so strict '>' keeps the lowest index.
// Selection round: static 8-chunk tree + 6-step shfl_xor butterfly; owning
// lane repairs its chunk by re-reading 4 float4s (L2-hot) with skip-list.
// Then exact f64 re-rank of the NCAND candidates, softmax, gather-combine.
// ---------------------------------------------------------------------------
__global__ __launch_bounds__(256) void topk_kernel(const float* __restrict__ att,
                                                   const float* __restrict__ z,
                                                   const float* __restrict__ centers,
                                                   const float* __restrict__ mus,
                                                   float* __restrict__ out) {
  const int lane = threadIdx.x & 63;
  const int row  = blockIdx.x * 4 + (threadIdx.x >> 6);
  const float4* arow4 = (const float4*)(att + (size_t)row * NC);

  // ---- pass 1: per-lane chunk maxima, fully coalesced ----
  float cmv[8]; int cmi[8];
#pragma unroll
  for (int c = 0; c < 8; ++c) {
    float bv = -INFINITY; int bi = 0x7FFFFFFF;
#pragma unroll
    for (int q = 0; q < 4; ++q) {
      float4 v = arow4[c * 256 + q * 64 + lane];
      const int ib = c * 1024 + q * 256 + lane * 4;
      if (v.x > bv) { bv = v.x; bi = ib + 0; }
      if (v.y > bv) { bv = v.y; bi = ib + 1; }
      if (v.z > bv) { bv = v.z; bi = ib + 2; }
      if (v.w > bv) { bv = v.w; bi = ib + 3; }
    }
    cmv[c] = bv; cmi[c] = bi;
  }

  int selIdx[NCAND];
#pragma unroll
  for (int s = 0; s < NCAND; ++s) selIdx[s] = -1;

#pragma unroll
  for (int it = 0; it < NCAND; ++it) {
    float v = cmv[0]; int i = cmi[0];
#pragma unroll
    for (int c = 1; c < 8; ++c)
      if (cmv[c] > v || (cmv[c] == v && cmi[c] < i)) { v = cmv[c]; i = cmi[c]; }
#pragma unroll
    for (int off = 32; off > 0; off >>= 1) {
      float ov = __shfl_xor(v, off);
      int   oi = __shfl_xor(i, off);
      if (ov > v || (ov == v && oi < i)) { v = ov; i = oi; }
    }
    selIdx[it] = i;

    // owning lane repairs its chunk max (skip already-selected indices)
    const int ol = (i >> 2) & 63;
    const int oc = i >> 10;
    if (lane == ol) {
      float nv = -INFINITY; int ni = 0x7FFFFFFF;
#pragma unroll
      for (int q = 0; q < 4; ++q) {
        float4 v4 = arow4[oc * 256 + q * 64 + lane];
        float vv[4] = {v4.x, v4.y, v4.z, v4.w};
#pragma unroll
        for (int e = 0; e < 4; ++e) {
          const int idx = oc * 1024 + q * 256 + lane * 4 + e;
          bool skip = false;
#pragma unroll
          for (int s = 0; s < NCAND; ++s) skip |= (idx == selIdx[s]);
          if (!skip && vv[e] > nv) { nv = vv[e]; ni = idx; }
        }
      }
#pragma unroll
      for (int c = 0; c < 8; ++c) if (c == oc) { cmv[c] = nv; cmi[c] = ni; }
    }
  }

  // ---- exact f64 re-computation of the NCAND candidates ----
  const float* zrow = z + (size_t)row * DIM;
  const int d0 = lane * 8;
  const float4 za = *(const float4*)(zrow + d0);
  const float4 zb = *(const float4*)(zrow + d0 + 4);
  const float myz2 = g_z2[row];

  float exv[NCAND];
#pragma unroll
  for (int c = 0; c < NCAND; ++c) {
    const int ci = selIdx[c];
    const float* cp = centers + (size_t)ci * DIM + d0;
    float4 ca = *(const float4*)(cp);
    float4 cb = *(const float4*)(cp + 4);
    double p = (double)za.x * ca.x + (double)za.y * ca.y +
               (double)za.z * ca.z + (double)za.w * ca.w +
               (double)zb.x * cb.x + (double)zb.y * cb.y +
               (double)zb.z * cb.z + (double)zb.w * cb.w;
#pragma unroll
    for (int off = 32; off > 0; off >>= 1) p += __shfl_xor(p, off);
    float dotf = (float)p;
    float t   = __fadd_rn(myz2, g_c2[ci]);
    float sq  = __fsub_rn(t, __fmul_rn(2.0f, dotf));
    float d   = sqrtf(fmaxf(sq, 0.0f));
    float den = __fadd_rn(__fmul_rn(d, d), 1e-6f);
    exv[c] = __fdiv_rn(mus[ci], den);
  }

  // ---- re-rank NCAND by (exact value desc, index asc), take top-5 ----
  bool used[NCAND];
#pragma unroll
  for (int c = 0; c < NCAND; ++c) used[c] = false;
  float tv[KEXP]; int tix[KEXP];
#pragma unroll
  for (int s = 0; s < KEXP; ++s) {
    float bv = -INFINITY; int bi = 0x7FFFFFFF; int bc = 0;
#pragma unroll
    for (int c = 0; c < NCAND; ++c) {
      if (!used[c] && (exv[c] > bv || (exv[c] == bv && selIdx[c] < bi))) {
        bv = exv[c]; bi = selIdx[c]; bc = c;
      }
    }
#pragma unroll
    for (int c = 0; c < NCAND; ++c) if (c == bc) used[c] = true;
    tv[s] = bv; tix[s] = bi;
  }

  // ---- softmax over the 5 exact values (tv[0] is the max) ----
  float m = tv[0];
  float w[KEXP];
  float s = 0.0f;
#pragma unroll
  for (int k = 0; k < KEXP; ++k) { w[k] = expf(tv[k] - m); s += w[k]; }
#pragma unroll
  for (int k = 0; k < KEXP; ++k) w[k] /= s;

  // ---- combine: out = 0.7*z + 0.3*sum_k w[k]*centers[tix[k]] ----
  float comb[8] = {0, 0, 0, 0, 0, 0, 0, 0};
#pragma unroll
  for (int k = 0; k < KEXP; ++k) {
    const float* cp = centers + (size_t)tix[k] * DIM + d0;
    float4 a = *(const float4*)(cp);
    float4 b = *(const float4*)(cp + 4);
    comb[0] += w[k] * a.x; comb[1] += w[k] * a.y;
    comb[2] += w[k] * a.z; comb[3] += w[k] * a.w;
    comb[4] += w[k] * b.x; comb[5] += w[k] * b.y;
    comb[6] += w[k] * b.z; comb[7] += w[k] * b.w;
  }
  const float zv[8] = {za.x, za.y, za.z, za.w, zb.x, zb.y, zb.z, zb.w};
  float o[8];
#pragma unroll
  for (int e = 0; e < 8; ++e)
    o[e] = __fadd_rn(__fmul_rn(0.7f, zv[e]), __fmul_rn(0.3f, comb[e]));
  *(float4*)(out + (size_t)row * DIM + d0)     = *(float4*)&o[0];
  *(float4*)(out + (size_t)row * DIM + d0 + 4) = *(float4*)&o[4];
}

// ---------------------------------------------------------------------------
extern "C" void kernel_launch(void* const* d_in, const int* in_sizes, int n_in,
                              void* d_out, int out_size, void* d_ws, size_t ws_size,
                              hipStream_t stream) {
  const float* z       = (const float*)d_in[0];
  const float* centers = (const float*)d_in[1];
  const float* mus     = (const float*)d_in[2];
  float* out      = (float*)d_out;
  float* expanded = out;
  float* att      = out + (size_t)BATCH * DIM;

  convert_kernel<<<(BATCH + NC) * DIM / (256 * 8), 256, 0, stream>>>(z, centers);
  norms_kernel<<<BATCH + NC, 128, 0, stream>>>(z, centers);
  dim3 grid(NC / BN, BATCH / BM);
  attr_bf16<<<grid, 256, 0, stream>>>(mus, att);
  topk_kernel<<<BATCH / 4, 256, 0, stream>>>(att, z, centers, mus, expanded);
}

// Round 6
// 155.077 us; speedup vs baseline: 3.1666x; 1.1114x over previous
//
#include <hip/hip_runtime.h>
#include <math.h>

#define BATCH 4096
#define NC    8192
#define DIM   512
#define KEXP  5
#define NCAND 10

using bf16x8 = __attribute__((ext_vector_type(8))) short;
using f32x4  = __attribute__((ext_vector_type(4))) float;
typedef unsigned long long u64;

// module-scope device buffers (no hipMalloc; deterministic, rewritten every call)
__device__ unsigned short g_zbf[BATCH * DIM];   // 4 MB bf16(z)
__device__ unsigned short g_cbf[NC * DIM];      // 8 MB bf16(centers)
__device__ float g_z2[BATCH];
__device__ float g_c2[NC];

__device__ __forceinline__ unsigned short rtne_bf16(float f) {
  unsigned u = __float_as_uint(f);
  u += 0x7FFFu + ((u >> 16) & 1u);
  return (unsigned short)(u >> 16);
}

__device__ __forceinline__ void gload16(const void* g, void* l) {
  __builtin_amdgcn_global_load_lds(
      (const __attribute__((address_space(1))) void*)g,
      (__attribute__((address_space(3))) void*)l, 16, 0, 0);
}

// ---------------------------------------------------------------------------
// Kernel 0: f32 -> bf16 (RTN) one-shot conversion of z and centers.
// ---------------------------------------------------------------------------
__global__ __launch_bounds__(256) void convert_kernel(const float* __restrict__ z,
                                                      const float* __restrict__ c) {
  const size_t i = ((size_t)blockIdx.x * 256 + threadIdx.x) * 8;
  const size_t zn = (size_t)BATCH * DIM;
  const float* src;
  unsigned short* dst;
  size_t off;
  if (i < zn) { src = z; dst = g_zbf; off = i; }
  else        { src = c; dst = g_cbf; off = i - zn; }
  float4 a = *(const float4*)(src + off);
  float4 b = *(const float4*)(src + off + 4);
  uint4 o;
  o.x = (unsigned)rtne_bf16(a.x) | ((unsigned)rtne_bf16(a.y) << 16);
  o.y = (unsigned)rtne_bf16(a.z) | ((unsigned)rtne_bf16(a.w) << 16);
  o.z = (unsigned)rtne_bf16(b.x) | ((unsigned)rtne_bf16(b.y) << 16);
  o.w = (unsigned)rtne_bf16(b.z) | ((unsigned)rtne_bf16(b.w) << 16);
  *(uint4*)(dst + off) = o;
}

// ---------------------------------------------------------------------------
// Kernel 1: row squared-norms, f64 accumulation.
// ---------------------------------------------------------------------------
__global__ __launch_bounds__(128) void norms_kernel(const float* __restrict__ z,
                                                    const float* __restrict__ c) {
  int row = blockIdx.x;
  const float* src;
  float* dst;
  if (row < BATCH) { src = z + (size_t)row * DIM; dst = g_z2 + row; }
  else             { src = c + (size_t)(row - BATCH) * DIM; dst = g_c2 + (row - BATCH); }
  int t = threadIdx.x;
  float4 v = ((const float4*)src)[t];
  double acc = (double)v.x * v.x + (double)v.y * v.y + (double)v.z * v.z + (double)v.w * v.w;
#pragma unroll
  for (int off = 32; off > 0; off >>= 1) acc += __shfl_down(acc, off);
  __shared__ double wsum[2];
  if ((t & 63) == 0) wsum[t >> 6] = acc;
  __syncthreads();
  if (t == 0) *dst = (float)(wsum[0] + wsum[1]);
}

// ---------------------------------------------------------------------------
// Kernel 2: attractions via single-term bf16 MFMA GEMM (unchanged, verified).
// ---------------------------------------------------------------------------
#define BM  128
#define BN  128
#define BKK 64

__global__ __launch_bounds__(256) void attr_bf16(const float* __restrict__ mus,
                                                 float* __restrict__ att) {
  __shared__ __align__(16) unsigned short Ah[BM * BKK];
  __shared__ __align__(16) unsigned short Bh[BM * BKK];

  const int tid  = threadIdx.x;
  const int lane = tid & 63;
  const int wid  = tid >> 6;
  const int wm   = wid >> 1;
  const int wn   = wid & 1;

  const int flat = blockIdx.y * gridDim.x + blockIdx.x;
  const int swz  = (flat & 7) * 256 + (flat >> 3);
  const int col0 = (swz & 63) * BN;
  const int row0 = (swz >> 6) * BM;

  f32x4 acc[4][4] = {};

  const unsigned short* Ag = g_zbf + (size_t)row0 * DIM;
  const unsigned short* Bg = g_cbf + (size_t)col0 * DIM;

  const int crow = lane >> 3;
  const int gsw  = (lane & 7) ^ crow;

  for (int k0 = 0; k0 < DIM; k0 += BKK) {
#pragma unroll
    for (int j = 0; j < 4; ++j) {
      const int base_row = (wid * 4 + j) * 8;
      const int r = base_row + crow;
      gload16(Ag + (size_t)r * DIM + k0 + gsw * 8, Ah + base_row * 64);
      gload16(Bg + (size_t)r * DIM + k0 + gsw * 8, Bh + base_row * 64);
    }
    __syncthreads();

#pragma unroll
    for (int kk = 0; kk < 2; ++kk) {
      bf16x8 fa[4], fb[4];
#pragma unroll
      for (int i = 0; i < 4; ++i) {
        const int r = wm * 64 + i * 16 + (lane & 15);
        const int g = (kk * 4 + (lane >> 4)) ^ (r & 7);
        fa[i] = *(const bf16x8*)((const char*)Ah + r * 128 + g * 16);
      }
#pragma unroll
      for (int j2 = 0; j2 < 4; ++j2) {
        const int r = wn * 64 + j2 * 16 + (lane & 15);
        const int g = (kk * 4 + (lane >> 4)) ^ (r & 7);
        fb[j2] = *(const bf16x8*)((const char*)Bh + r * 128 + g * 16);
      }
#pragma unroll
      for (int i = 0; i < 4; ++i)
#pragma unroll
        for (int j2 = 0; j2 < 4; ++j2)
          acc[i][j2] = __builtin_amdgcn_mfma_f32_16x16x32_bf16(fa[i], fb[j2], acc[i][j2], 0, 0, 0);
    }
    __syncthreads();
  }

#pragma unroll
  for (int i = 0; i < 4; ++i) {
    const int mrow = row0 + wm * 64 + i * 16 + (lane >> 4) * 4;
    float zz[4];
#pragma unroll
    for (int r = 0; r < 4; ++r) zz[r] = g_z2[mrow + r];
#pragma unroll
    for (int j = 0; j < 4; ++j) {
      const int gc = col0 + wn * 64 + j * 16 + (lane & 15);
      const float cc = g_c2[gc];
      const float mu = mus[gc];
#pragma unroll
      for (int r = 0; r < 4; ++r) {
        float t   = __fadd_rn(zz[r], cc);
        float sq  = __fsub_rn(t, __fmul_rn(2.0f, acc[i][j][r]));
        float d   = sqrtf(fmaxf(sq, 0.0f));
        float den = __fadd_rn(__fmul_rn(d, d), 1e-6f);
        att[(size_t)(mrow + r) * NC + gc] = __fdiv_rn(mu, den);
      }
    }
  }
}

// ---------------------------------------------------------------------------
// Kernel 3: wave-per-row top-NCAND via packed-key pop-lists.
// Key = (f32 bits << 32) | (0xFFFFFFFF - idx): u64 order == (value desc,
// index asc). Pass 1: per lane, 8 chunks x sorted top-4 key list (branchless
// insertion). Round: 7-cmp chunk tree + 6-step u64 butterfly + pop by
// key-equality shift (no memory, no rescan, no skip-list). Round loop ROLLED
// (small I$ footprint); selected indices spill to a tiny per-wave LDS array.
// Then exact f64 re-rank of NCAND candidates, softmax, gather-combine.
// ---------------------------------------------------------------------------
__global__ __launch_bounds__(256, 4) void topk_kernel(const float* __restrict__ att,
                                                      const float* __restrict__ z,
                                                      const float* __restrict__ centers,
                                                      const float* __restrict__ mus,
                                                      float* __restrict__ out) {
  __shared__ int selLds[4][16];
  const int lane = threadIdx.x & 63;
  const int wv   = threadIdx.x >> 6;
  const int row  = blockIdx.x * 4 + wv;
  const float4* arow4 = (const float4*)(att + (size_t)row * NC);

  // ---- pass 1: 8 chunks x top-4 sorted u64 keys, coalesced loads ----
  u64 k[8][4];
#pragma unroll
  for (int c = 0; c < 8; ++c) {
#pragma unroll
    for (int j = 0; j < 4; ++j) k[c][j] = 0ull;
#pragma unroll
    for (int q = 0; q < 4; ++q) {
      float4 v4 = arow4[c * 256 + q * 64 + lane];
      const unsigned ib = (unsigned)(c * 1024 + q * 256 + lane * 4);
      const float vv[4] = {v4.x, v4.y, v4.z, v4.w};
#pragma unroll
      for (int e = 0; e < 4; ++e) {
        u64 nk = ((u64)__float_as_uint(vv[e]) << 32) | (u64)(0xFFFFFFFFu - (ib + e));
        bool g0 = nk > k[c][0], g1 = nk > k[c][1], g2 = nk > k[c][2], g3 = nk > k[c][3];
        u64 t0 = k[c][0], t1 = k[c][1], t2 = k[c][2];
        k[c][0] = g0 ? nk : k[c][0];
        k[c][1] = g0 ? t0 : (g1 ? nk : k[c][1]);
        k[c][2] = g1 ? t1 : (g2 ? nk : k[c][2]);
        k[c][3] = g2 ? t2 : (g3 ? nk : k[c][3]);
      }
    }
  }

  // ---- NCAND selection rounds (rolled loop, registers only) ----
  for (int it = 0; it < NCAND; ++it) {
    u64 b = k[0][0];
#pragma unroll
    for (int c = 1; c < 8; ++c) b = (k[c][0] > b) ? k[c][0] : b;
#pragma unroll
    for (int off = 32; off > 0; off >>= 1) {
      u64 o = __shfl_xor(b, off);
      b = (o > b) ? o : b;
    }
    if (lane == 0) selLds[wv][it] = (int)(0xFFFFFFFFu - (unsigned)(b & 0xFFFFFFFFu));
    // pop: keys are unique, so exactly one (lane, chunk) head equals b
#pragma unroll
    for (int c = 0; c < 8; ++c) {
      bool hit = (k[c][0] == b);
      k[c][0] = hit ? k[c][1] : k[c][0];
      k[c][1] = hit ? k[c][2] : k[c][1];
      k[c][2] = hit ? k[c][3] : k[c][2];
      k[c][3] = hit ? 0ull    : k[c][3];
    }
  }

  // ---- exact f64 re-computation of the NCAND candidates ----
  const float* zrow = z + (size_t)row * DIM;
  const int d0 = lane * 8;
  const float4 za = *(const float4*)(zrow + d0);
  const float4 zb = *(const float4*)(zrow + d0 + 4);
  const float myz2 = g_z2[row];

  double p[NCAND];
  int cidx[NCAND];
#pragma unroll
  for (int c = 0; c < NCAND; ++c) {
    cidx[c] = selLds[wv][c];
    const float* cp = centers + (size_t)cidx[c] * DIM + d0;
    float4 ca = *(const float4*)(cp);
    float4 cb = *(const float4*)(cp + 4);
    p[c] = (double)za.x * ca.x + (double)za.y * ca.y +
           (double)za.z * ca.z + (double)za.w * ca.w +
           (double)zb.x * cb.x + (double)zb.y * cb.y +
           (double)zb.z * cb.z + (double)zb.w * cb.w;
  }
  // interleaved butterflies: 10 independent chains pipeline
#pragma unroll
  for (int off = 32; off > 0; off >>= 1) {
#pragma unroll
    for (int c = 0; c < NCAND; ++c) p[c] += __shfl_xor(p[c], off);
  }

  float exv[NCAND];
#pragma unroll
  for (int c = 0; c < NCAND; ++c) {
    const int ci = cidx[c];
    float dotf = (float)p[c];
    float t   = __fadd_rn(myz2, g_c2[ci]);
    float sq  = __fsub_rn(t, __fmul_rn(2.0f, dotf));
    float d   = sqrtf(fmaxf(sq, 0.0f));
    float den = __fadd_rn(__fmul_rn(d, d), 1e-6f);
    exv[c] = __fdiv_rn(mus[ci], den);
  }

  // ---- re-rank NCAND by (exact value desc, index asc), take top-5 ----
  unsigned used = 0;
  float tv[KEXP]; int tix[KEXP];
#pragma unroll
  for (int s = 0; s < KEXP; ++s) {
    float bv = -INFINITY; int bi = 0x7FFFFFFF; int bc = 0;
#pragma unroll
    for (int c = 0; c < NCAND; ++c) {
      bool ok = (used & (1u << c)) == 0;
      if (ok && (exv[c] > bv || (exv[c] == bv && cidx[c] < bi))) {
        bv = exv[c]; bi = cidx[c]; bc = c;
      }
    }
    used |= (1u << bc);
    tv[s] = bv; tix[s] = bi;
  }

  // ---- softmax over the 5 exact values (tv[0] is the max) ----
  float m = tv[0];
  float w[KEXP];
  float s = 0.0f;
#pragma unroll
  for (int kk = 0; kk < KEXP; ++kk) { w[kk] = expf(tv[kk] - m); s += w[kk]; }
#pragma unroll
  for (int kk = 0; kk < KEXP; ++kk) w[kk] /= s;

  // ---- combine: out = 0.7*z + 0.3*sum_k w[k]*centers[tix[k]] ----
  float comb[8] = {0, 0, 0, 0, 0, 0, 0, 0};
#pragma unroll
  for (int kk = 0; kk < KEXP; ++kk) {
    const float* cp = centers + (size_t)tix[kk] * DIM + d0;
    float4 a = *(const float4*)(cp);
    float4 bq = *(const float4*)(cp + 4);
    comb[0] += w[kk] * a.x;  comb[1] += w[kk] * a.y;
    comb[2] += w[kk] * a.z;  comb[3] += w[kk] * a.w;
    comb[4] += w[kk] * bq.x; comb[5] += w[kk] * bq.y;
    comb[6] += w[kk] * bq.z; comb[7] += w[kk] * bq.w;
  }
  const float zv[8] = {za.x, za.y, za.z, za.w, zb.x, zb.y, zb.z, zb.w};
  float o[8];
#pragma unroll
  for (int e = 0; e < 8; ++e)
    o[e] = __fadd_rn(__fmul_rn(0.7f, zv[e]), __fmul_rn(0.3f, comb[e]));
  *(float4*)(out + (size_t)row * DIM + d0)     = *(float4*)&o[0];
  *(float4*)(out + (size_t)row * DIM + d0 + 4) = *(float4*)&o[4];
}

// ---------------------------------------------------------------------------
extern "C" void kernel_launch(void* const* d_in, const int* in_sizes, int n_in,
                              void* d_out, int out_size, void* d_ws, size_t ws_size,
                              hipStream_t stream) {
  const float* z       = (const float*)d_in[0];
  const float* centers = (const float*)d_in[1];
  const float* mus     = (const float*)d_in[2];
  float* out      = (float*)d_out;
  float* expanded = out;
  float* att      = out + (size_t)BATCH * DIM;

  convert_kernel<<<(BATCH + NC) * DIM / (256 * 8), 256, 0, stream>>>(z, centers);
  norms_kernel<<<BATCH + NC, 128, 0, stream>>>(z, centers);
  dim3 grid(NC / BN, BATCH / BM);
  attr_bf16<<<grid, 256, 0, stream>>>(mus, att);
  topk_kernel<<<BATCH / 4, 256, 0, stream>>>(att, z, centers, mus, expanded);
}